// Round 5
// baseline (285.316 us; speedup 1.0000x reference)
//
#include <hip/hip_runtime.h>
#include <hip/hip_bf16.h>

// z[b,n] = (1/196) * sum_{c,c'} (Xf[b] Yf[b]^T)[c,c'] * (w0[n] w1[n]^T)[c,c'] ; out = softmax_n(z + bias)
// M and W share a FRAG-PACKED layout (any (c,c') permutation applied to both preserves the
// trace-dot): flat = tile*16384 + wave*4096 + pair*512 + lane*8 + half*4 + e  (pair=frag>>1).
// Stage 1 (ONE launch, 4608 blocks): bid<2304 -> M[b] (bf16 /196, XCD-swizzled); else W[n].
// Stage 2: split-K partials (f32)  -> zpartial, 1152 blocks
// Stage 3: reduce + bias + softmax -> d_out (f32, 64x64)

typedef float f32x4 __attribute__((ext_vector_type(4)));
typedef __bf16 bf16x8 __attribute__((ext_vector_type(8)));
typedef __bf16 bf16x4 __attribute__((ext_vector_type(4)));

#define KFLAT ((size_t)(768 * 768))
#define LDP 40   // padded LDS row: 80 B stride, keeps 16-B alignment; ~2-way aliasing

// Unified Gram kernel. First 2304 blocks: M[b] = X Y^T / 196 (K=196: 6 full + 4-tail).
// Last 2304 blocks: W[n] = w0 w1^T (K=32: 1 full step, no tail).
__global__ __launch_bounds__(256) void gram_v4(
    const float* __restrict__ X, const float* __restrict__ Y,
    const float* __restrict__ w0, const float* __restrict__ w1,
    __bf16* __restrict__ Mout, __bf16* __restrict__ Wout)
{
    const int t    = threadIdx.x;
    const int lane = t & 63;
    const int wid  = t >> 6;
    const int wr   = wid >> 1, wc = wid & 1;
    const int lr   = lane & 15, lq = lane >> 4;

    const bool wmode = (blockIdx.x >= 2304);
    int bx, bat, lda, nfull, tail;
    const float *A, *B;
    __bf16* Out;
    float scale;
    if (!wmode) {
        const int orig = (blockIdx.x & 7) * 288 + (blockIdx.x >> 3);  // XCD swizzle
        bat = orig / 36; bx = orig % 36;
        A = X + (size_t)bat * (768 * 196);
        B = Y + (size_t)bat * (768 * 196);
        Out = Mout; lda = 196; nfull = 6; tail = 1; scale = 1.0f / 196.0f;
    } else {
        const int wbid = blockIdx.x - 2304;
        bat = wbid / 36; bx = wbid % 36;
        A = w0 + (size_t)bat * (768 * 32);
        B = w1 + (size_t)bat * (768 * 32);
        Out = Wout; lda = 32; nfull = 1; tail = 0; scale = 1.0f;
    }
    const int c0 = (bx / 6) * 128, cc0 = (bx % 6) * 128;

    __shared__ __bf16 As[128][LDP];
    __shared__ __bf16 Bs[128][LDP];

    const int r = t >> 1;          // staging row 0..127
    const int h = t & 1;           // k-half (16 elems)
    const float* Ap = A + (size_t)(c0  + r) * lda + h * 16;
    const float* Bp = B + (size_t)(cc0 + r) * lda + h * 16;

    f32x4 acc[4][4];
#pragma unroll
    for (int i = 0; i < 4; ++i)
#pragma unroll
        for (int j = 0; j < 4; ++j) acc[i][j] = (f32x4){0.f, 0.f, 0.f, 0.f};

    auto stage = [&](const f32x4* va, const f32x4* vb) {
        bf16x8 u;
#pragma unroll
        for (int e = 0; e < 4; ++e) { u[e] = (__bf16)va[0][e]; u[e+4] = (__bf16)va[1][e]; }
        *(bf16x8*)&As[r][h * 16] = u;
#pragma unroll
        for (int e = 0; e < 4; ++e) { u[e] = (__bf16)va[2][e]; u[e+4] = (__bf16)va[3][e]; }
        *(bf16x8*)&As[r][h * 16 + 8] = u;
#pragma unroll
        for (int e = 0; e < 4; ++e) { u[e] = (__bf16)vb[0][e]; u[e+4] = (__bf16)vb[1][e]; }
        *(bf16x8*)&Bs[r][h * 16] = u;
#pragma unroll
        for (int e = 0; e < 4; ++e) { u[e] = (__bf16)vb[2][e]; u[e+4] = (__bf16)vb[3][e]; }
        *(bf16x8*)&Bs[r][h * 16 + 8] = u;
    };

    auto compute = [&]() {
        bf16x8 af[4], bfr[4];
#pragma unroll
        for (int m = 0; m < 4; ++m) af[m]  = *(const bf16x8*)&As[wr * 64 + m * 16 + lr][lq * 8];
#pragma unroll
        for (int n = 0; n < 4; ++n) bfr[n] = *(const bf16x8*)&Bs[wc * 64 + n * 16 + lr][lq * 8];
#pragma unroll
        for (int m = 0; m < 4; ++m)
#pragma unroll
            for (int n = 0; n < 4; ++n)
                acc[m][n] = __builtin_amdgcn_mfma_f32_16x16x32_bf16(af[m], bfr[n], acc[m][n], 0, 0, 0);
    };

    f32x4 pa[4], pb[4], na[4], nb[4];
#pragma unroll
    for (int j = 0; j < 4; ++j) {
        pa[j] = *(const f32x4*)(Ap + j * 4); pb[j] = *(const f32x4*)(Bp + j * 4);
        na[j] = (f32x4){0.f, 0.f, 0.f, 0.f}; nb[j] = (f32x4){0.f, 0.f, 0.f, 0.f};
    }

    for (int kk = 0; kk < nfull; ++kk) {
        __syncthreads();
        stage(pa, pb);
        if (kk + 1 < nfull) {
            const int o = (kk + 1) * 32;
#pragma unroll
            for (int j = 0; j < 4; ++j) { na[j] = *(const f32x4*)(Ap + o + j * 4); nb[j] = *(const f32x4*)(Bp + o + j * 4); }
        }
        __syncthreads();
        compute();
#pragma unroll
        for (int j = 0; j < 4; ++j) { pa[j] = na[j]; pb[j] = nb[j]; }
    }

    if (tail) {  // 4 valid k-cols at nfull*32, rest zero
        __syncthreads();
        const int tr = t & 127;
        const float* src = (t < 128) ? (A + (size_t)(c0  + tr) * lda + nfull * 32)
                                     : (B + (size_t)(cc0 + tr) * lda + nfull * 32);
        f32x4 v = *(const f32x4*)src;
        __bf16* dst = (t < 128) ? &As[tr][0] : &Bs[tr][0];
        bf16x4 q4 = { (__bf16)v.x, (__bf16)v.y, (__bf16)v.z, (__bf16)v.w };
        bf16x4 z4; bf16x8 z8;
#pragma unroll
        for (int e = 0; e < 4; ++e) z4[e] = (__bf16)0.0f;
#pragma unroll
        for (int e = 0; e < 8; ++e) z8[e] = (__bf16)0.0f;
        *(bf16x4*)dst        = q4;
        *(bf16x4*)(dst + 4)  = z4;
        *(bf16x8*)(dst + 8)  = z8;
        *(bf16x8*)(dst + 16) = z8;
        *(bf16x8*)(dst + 24) = z8;
        __syncthreads();
        compute();
    }

    // frag-packed output: 8 stores of 16 B/lane (pair-packed: frags 2p and 2p+1)
    __bf16* Ob = Out + (size_t)bat * KFLAT + (size_t)bx * 16384 + wid * 4096 + lane * 8;
#pragma unroll
    for (int p = 0; p < 8; ++p) {
        const int f0 = p * 2, f1 = f0 + 1;
        const f32x4 u0 = acc[f0 >> 2][f0 & 3];
        const f32x4 u1 = acc[f1 >> 2][f1 & 3];
        bf16x8 o;
#pragma unroll
        for (int e = 0; e < 4; ++e) { o[e] = (__bf16)(u0[e] * scale); o[e + 4] = (__bf16)(u1[e] * scale); }
        *(bf16x8*)(Ob + p * 512) = o;
    }
}

// Split-K: 1152 blocks x 4 waves x 4 steps (= 18432 k-steps of 32). Prefetched loads,
// 32 KB staged pairwise LDS reduce, row-major 64x64 f32 partial per block.
__global__ __launch_bounds__(256) void zpartial(
    const __bf16* __restrict__ M, const __bf16* __restrict__ W,
    float* __restrict__ P, int steps)
{
    __shared__ float red[2][4096];   // 32 KB

    const int t    = threadIdx.x;
    const int lane = t & 63;
    const int wid  = t >> 6;
    const int lr = lane & 15, lq = lane >> 4;
    const size_t KK = KFLAT;

    f32x4 acc[4][4];
#pragma unroll
    for (int i = 0; i < 4; ++i)
#pragma unroll
        for (int j = 0; j < 4; ++j) acc[i][j] = (f32x4){0.f, 0.f, 0.f, 0.f};

    const size_t s0 = ((size_t)blockIdx.x * 4 + wid) * steps;
    const __bf16* Mp = M + (size_t)lr * KK + (size_t)lq * 8 + s0 * 32;
    const __bf16* Wp = W + (size_t)lr * KK + (size_t)lq * 8 + s0 * 32;

    bf16x8 a[4], b[4], a2[4], b2[4];
#pragma unroll
    for (int i = 0; i < 4; ++i) {
        a[i] = *(const bf16x8*)(Mp + i * 16 * KK); b[i] = *(const bf16x8*)(Wp + i * 16 * KK);
        a2[i] = a[i]; b2[i] = b[i];
    }

    for (int s = 0; s < steps; ++s) {
        if (s + 1 < steps) {
            const size_t o = (size_t)(s + 1) * 32;
#pragma unroll
            for (int i = 0; i < 4; ++i) { a2[i] = *(const bf16x8*)(Mp + i * 16 * KK + o); b2[i] = *(const bf16x8*)(Wp + i * 16 * KK + o); }
        }
#pragma unroll
        for (int i = 0; i < 4; ++i)
#pragma unroll
            for (int j = 0; j < 4; ++j)
                acc[i][j] = __builtin_amdgcn_mfma_f32_16x16x32_bf16(a[i], b[j], acc[i][j], 0, 0, 0);
#pragma unroll
        for (int i = 0; i < 4; ++i) { a[i] = a2[i]; b[i] = b2[i]; }
    }

    // staged reduce: w2,w3 stash; w0,w1 add; w1 stash; w0 writes row-major
    const int fbase = lane * 4;
    if (wid >= 2) {
#pragma unroll
        for (int i = 0; i < 4; ++i)
#pragma unroll
            for (int j = 0; j < 4; ++j)
                *(f32x4*)&red[wid - 2][(i * 4 + j) * 256 + fbase] = acc[i][j];
    }
    __syncthreads();
    if (wid < 2) {
#pragma unroll
        for (int i = 0; i < 4; ++i)
#pragma unroll
            for (int j = 0; j < 4; ++j)
                acc[i][j] += *(const f32x4*)&red[wid][(i * 4 + j) * 256 + fbase];
    }
    __syncthreads();
    if (wid == 1) {
#pragma unroll
        for (int i = 0; i < 4; ++i)
#pragma unroll
            for (int j = 0; j < 4; ++j)
                *(f32x4*)&red[0][(i * 4 + j) * 256 + fbase] = acc[i][j];
    }
    __syncthreads();
    if (wid == 0) {
        float* Pb = P + (size_t)blockIdx.x * 4096;
#pragma unroll
        for (int i = 0; i < 4; ++i)
#pragma unroll
            for (int j = 0; j < 4; ++j) {
                f32x4 v = acc[i][j] + *(const f32x4*)&red[0][(i * 4 + j) * 256 + fbase];
#pragma unroll
                for (int e = 0; e < 4; ++e) {
                    const int row = i * 16 + lq * 4 + e;
                    const int col = j * 16 + lr;
                    Pb[row * 64 + col] = v[e];
                }
            }
    }
}

// Reduce partials + bias + softmax. 64 blocks (b) x 256 threads (4-way chunk split per n).
__global__ __launch_bounds__(256) void finalize(
    const float* __restrict__ P, const float* __restrict__ bias,
    float* __restrict__ out, int nchunks)
{
    __shared__ float red[4][64];
    const int b = blockIdx.x, n = threadIdx.x & 63, q = threadIdx.x >> 6;
    float s = 0.f;
    for (int c = q; c < nchunks; c += 4) s += P[(size_t)c * 4096 + b * 64 + n];
    red[q][n] = s;
    __syncthreads();
    if (q == 0) {
        float z = red[0][n] + red[1][n] + red[2][n] + red[3][n] + bias[n];
        float mx = z;
#pragma unroll
        for (int off = 32; off; off >>= 1) mx = fmaxf(mx, __shfl_xor(mx, off));
        float e = __expf(z - mx);
        float den = e;
#pragma unroll
        for (int off = 32; off; off >>= 1) den += __shfl_xor(den, off);
        out[b * 64 + n] = e / den;
    }
}

extern "C" void kernel_launch(void* const* d_in, const int* in_sizes, int n_in,
                              void* d_out, int out_size, void* d_ws, size_t ws_size,
                              hipStream_t stream) {
    const float* X    = (const float*)d_in[0];  // [64,768,14,14]
    const float* Y    = (const float*)d_in[1];  // [64,768,14,14]
    const float* w    = (const float*)d_in[2];  // [2,64,768,32]
    const float* bias = (const float*)d_in[3];  // [64]
    float* out = (float*)d_out;                 // [64,64] f32

    char* ws = (char*)d_ws;
    __bf16* Mws = (__bf16*)ws;                      // 72 MiB
    __bf16* Wws = (__bf16*)(ws + 75497472);         // 72 MiB
    float*  Pws = (float*)(ws + 150994944);         // 1152*4096*4 = 18 MiB (total 162 MiB)

    const float* w0 = w;
    const float* w1 = w + (size_t)64 * 768 * 32;

    // Stage 1: M and W in ONE launch (first 2304 blocks = M, last 2304 = W)
    gram_v4<<<4608, 256, 0, stream>>>(X, Y, w0, w1, Mws, Wws);
    // Stage 2: split-K partials (1152 blocks x 4 waves x 4 steps)
    zpartial<<<1152, 256, 0, stream>>>(Mws, Wws, Pws, 4);
    // Stage 3: reduce + bias + softmax
    finalize<<<64, 256, 0, stream>>>(Pws, bias, out, 1152);
}

// Round 6
// 270.673 us; speedup vs baseline: 1.0541x; 1.0541x over previous
//
#include <hip/hip_runtime.h>
#include <hip/hip_bf16.h>

// z[b,n] = (1/196) * sum_{c,c'} (Xf[b] Yf[b]^T)[c,c'] * (w0[n] w1[n]^T)[c,c'] ; out = softmax_n(z + bias)
// M and W share a FRAG-PACKED layout (any (c,c') permutation applied to both preserves the
// trace-dot): flat = tile*16384 + wave*4096 + pair*512 + lane*8 + half*4 + e  (pair=frag>>1).
// Stage 1 (ONE launch, 4608 blocks): bid<2304 -> M[b] (bf16 /196, XCD-swizzled); else W[n].
// Stage 2: split-K partials (f32)  -> zpartial, 1024 single-wave blocks x 18 steps (R1 config)
// Stage 3: reduce + bias + softmax -> d_out (f32, 64x64)

typedef float f32x4 __attribute__((ext_vector_type(4)));
typedef __bf16 bf16x8 __attribute__((ext_vector_type(8)));
typedef __bf16 bf16x4 __attribute__((ext_vector_type(4)));

#define KFLAT ((size_t)(768 * 768))
#define LDP 40   // padded LDS row: 80 B stride, keeps 16-B alignment; ~2-way aliasing

// Unified Gram kernel. First 2304 blocks: M[b] = X Y^T / 196 (K=196: 6 full + 4-tail).
// Last 2304 blocks: W[n] = w0 w1^T (K=32: 1 full step, no tail).
__global__ __launch_bounds__(256) void gram_v4(
    const float* __restrict__ X, const float* __restrict__ Y,
    const float* __restrict__ w0, const float* __restrict__ w1,
    __bf16* __restrict__ Mout, __bf16* __restrict__ Wout)
{
    const int t    = threadIdx.x;
    const int lane = t & 63;
    const int wid  = t >> 6;
    const int wr   = wid >> 1, wc = wid & 1;
    const int lr   = lane & 15, lq = lane >> 4;

    const bool wmode = (blockIdx.x >= 2304);
    int bx, bat, lda, nfull, tail;
    const float *A, *B;
    __bf16* Out;
    float scale;
    if (!wmode) {
        const int orig = (blockIdx.x & 7) * 288 + (blockIdx.x >> 3);  // XCD swizzle
        bat = orig / 36; bx = orig % 36;
        A = X + (size_t)bat * (768 * 196);
        B = Y + (size_t)bat * (768 * 196);
        Out = Mout; lda = 196; nfull = 6; tail = 1; scale = 1.0f / 196.0f;
    } else {
        const int wbid = blockIdx.x - 2304;
        bat = wbid / 36; bx = wbid % 36;
        A = w0 + (size_t)bat * (768 * 32);
        B = w1 + (size_t)bat * (768 * 32);
        Out = Wout; lda = 32; nfull = 1; tail = 0; scale = 1.0f;
    }
    const int c0 = (bx / 6) * 128, cc0 = (bx % 6) * 128;

    __shared__ __bf16 As[128][LDP];
    __shared__ __bf16 Bs[128][LDP];

    const int r = t >> 1;          // staging row 0..127
    const int h = t & 1;           // k-half (16 elems)
    const float* Ap = A + (size_t)(c0  + r) * lda + h * 16;
    const float* Bp = B + (size_t)(cc0 + r) * lda + h * 16;

    f32x4 acc[4][4];
#pragma unroll
    for (int i = 0; i < 4; ++i)
#pragma unroll
        for (int j = 0; j < 4; ++j) acc[i][j] = (f32x4){0.f, 0.f, 0.f, 0.f};

    auto stage = [&](const f32x4* va, const f32x4* vb) {
        bf16x8 u;
#pragma unroll
        for (int e = 0; e < 4; ++e) { u[e] = (__bf16)va[0][e]; u[e+4] = (__bf16)va[1][e]; }
        *(bf16x8*)&As[r][h * 16] = u;
#pragma unroll
        for (int e = 0; e < 4; ++e) { u[e] = (__bf16)va[2][e]; u[e+4] = (__bf16)va[3][e]; }
        *(bf16x8*)&As[r][h * 16 + 8] = u;
#pragma unroll
        for (int e = 0; e < 4; ++e) { u[e] = (__bf16)vb[0][e]; u[e+4] = (__bf16)vb[1][e]; }
        *(bf16x8*)&Bs[r][h * 16] = u;
#pragma unroll
        for (int e = 0; e < 4; ++e) { u[e] = (__bf16)vb[2][e]; u[e+4] = (__bf16)vb[3][e]; }
        *(bf16x8*)&Bs[r][h * 16 + 8] = u;
    };

    auto compute = [&]() {
        bf16x8 af[4], bfr[4];
#pragma unroll
        for (int m = 0; m < 4; ++m) af[m]  = *(const bf16x8*)&As[wr * 64 + m * 16 + lr][lq * 8];
#pragma unroll
        for (int n = 0; n < 4; ++n) bfr[n] = *(const bf16x8*)&Bs[wc * 64 + n * 16 + lr][lq * 8];
#pragma unroll
        for (int m = 0; m < 4; ++m)
#pragma unroll
            for (int n = 0; n < 4; ++n)
                acc[m][n] = __builtin_amdgcn_mfma_f32_16x16x32_bf16(af[m], bfr[n], acc[m][n], 0, 0, 0);
    };

    f32x4 pa[4], pb[4], na[4], nb[4];
#pragma unroll
    for (int j = 0; j < 4; ++j) {
        pa[j] = *(const f32x4*)(Ap + j * 4); pb[j] = *(const f32x4*)(Bp + j * 4);
        na[j] = (f32x4){0.f, 0.f, 0.f, 0.f}; nb[j] = (f32x4){0.f, 0.f, 0.f, 0.f};
    }

    for (int kk = 0; kk < nfull; ++kk) {
        __syncthreads();
        stage(pa, pb);
        if (kk + 1 < nfull) {
            const int o = (kk + 1) * 32;
#pragma unroll
            for (int j = 0; j < 4; ++j) { na[j] = *(const f32x4*)(Ap + o + j * 4); nb[j] = *(const f32x4*)(Bp + o + j * 4); }
        }
        __syncthreads();
        compute();
#pragma unroll
        for (int j = 0; j < 4; ++j) { pa[j] = na[j]; pb[j] = nb[j]; }
    }

    if (tail) {  // 4 valid k-cols at nfull*32, rest zero
        __syncthreads();
        const int tr = t & 127;
        const float* src = (t < 128) ? (A + (size_t)(c0  + tr) * lda + nfull * 32)
                                     : (B + (size_t)(cc0 + tr) * lda + nfull * 32);
        f32x4 v = *(const f32x4*)src;
        __bf16* dst = (t < 128) ? &As[tr][0] : &Bs[tr][0];
        bf16x4 q4 = { (__bf16)v.x, (__bf16)v.y, (__bf16)v.z, (__bf16)v.w };
        bf16x4 z4; bf16x8 z8;
#pragma unroll
        for (int e = 0; e < 4; ++e) z4[e] = (__bf16)0.0f;
#pragma unroll
        for (int e = 0; e < 8; ++e) z8[e] = (__bf16)0.0f;
        *(bf16x4*)dst        = q4;
        *(bf16x4*)(dst + 4)  = z4;
        *(bf16x8*)(dst + 8)  = z8;
        *(bf16x8*)(dst + 16) = z8;
        *(bf16x8*)(dst + 24) = z8;
        __syncthreads();
        compute();
    }

    // frag-packed output: 8 stores of 16 B/lane (pair-packed: frags 2p and 2p+1)
    __bf16* Ob = Out + (size_t)bat * KFLAT + (size_t)bx * 16384 + wid * 4096 + lane * 8;
#pragma unroll
    for (int p = 0; p < 8; ++p) {
        const int f0 = p * 2, f1 = f0 + 1;
        const f32x4 u0 = acc[f0 >> 2][f0 & 3];
        const f32x4 u1 = acc[f1 >> 2][f1 & 3];
        bf16x8 o;
#pragma unroll
        for (int e = 0; e < 4; ++e) { o[e] = (__bf16)(u0[e] * scale); o[e + 4] = (__bf16)(u1[e] * scale); }
        *(bf16x8*)(Ob + p * 512) = o;
    }
}

// Split-K, R1 config (measured best): 1024 single-wave blocks, 18 k-steps each.
// Each block writes its 64x64 f32 partial row-major to P[blk*4096 + ...].
__global__ __launch_bounds__(64) void zpartial(
    const __bf16* __restrict__ M, const __bf16* __restrict__ W,
    float* __restrict__ P, int steps)
{
    const int lane = threadIdx.x;
    const int lr = lane & 15, lq = lane >> 4;
    const size_t KK = KFLAT;  // 589824

    f32x4 acc[4][4];
#pragma unroll
    for (int i = 0; i < 4; ++i)
#pragma unroll
        for (int j = 0; j < 4; ++j) acc[i][j] = (f32x4){0.f, 0.f, 0.f, 0.f};

    const size_t s0 = (size_t)blockIdx.x * steps;
    for (int s = 0; s < steps; ++s) {
        const size_t k = (s0 + s) * 32 + (size_t)lq * 8;
        bf16x8 a[4], b[4];
#pragma unroll
        for (int i = 0; i < 4; ++i) a[i] = *(const bf16x8*)(M + (size_t)(i * 16 + lr) * KK + k);
#pragma unroll
        for (int j = 0; j < 4; ++j) b[j] = *(const bf16x8*)(W + (size_t)(j * 16 + lr) * KK + k);
#pragma unroll
        for (int i = 0; i < 4; ++i)
#pragma unroll
            for (int j = 0; j < 4; ++j)
                acc[i][j] = __builtin_amdgcn_mfma_f32_16x16x32_bf16(a[i], b[j], acc[i][j], 0, 0, 0);
    }

    float* Pb = P + (size_t)blockIdx.x * 4096;
#pragma unroll
    for (int i = 0; i < 4; ++i)
#pragma unroll
        for (int j = 0; j < 4; ++j)
#pragma unroll
            for (int e = 0; e < 4; ++e) {
                const int row = i * 16 + lq * 4 + e;
                const int col = j * 16 + lr;
                Pb[row * 64 + col] = acc[i][j][e];
            }
}

// Reduce partials + bias + softmax. 64 blocks (b) x 256 threads (4-way chunk split per n).
__global__ __launch_bounds__(256) void finalize(
    const float* __restrict__ P, const float* __restrict__ bias,
    float* __restrict__ out, int nchunks)
{
    __shared__ float red[4][64];
    const int b = blockIdx.x, n = threadIdx.x & 63, q = threadIdx.x >> 6;
    float s = 0.f;
    for (int c = q; c < nchunks; c += 4) s += P[(size_t)c * 4096 + b * 64 + n];
    red[q][n] = s;
    __syncthreads();
    if (q == 0) {
        float z = red[0][n] + red[1][n] + red[2][n] + red[3][n] + bias[n];
        float mx = z;
#pragma unroll
        for (int off = 32; off; off >>= 1) mx = fmaxf(mx, __shfl_xor(mx, off));
        float e = __expf(z - mx);
        float den = e;
#pragma unroll
        for (int off = 32; off; off >>= 1) den += __shfl_xor(den, off);
        out[b * 64 + n] = e / den;
    }
}

extern "C" void kernel_launch(void* const* d_in, const int* in_sizes, int n_in,
                              void* d_out, int out_size, void* d_ws, size_t ws_size,
                              hipStream_t stream) {
    const float* X    = (const float*)d_in[0];  // [64,768,14,14]
    const float* Y    = (const float*)d_in[1];  // [64,768,14,14]
    const float* w    = (const float*)d_in[2];  // [2,64,768,32]
    const float* bias = (const float*)d_in[3];  // [64]
    float* out = (float*)d_out;                 // [64,64] f32

    char* ws = (char*)d_ws;
    __bf16* Mws = (__bf16*)ws;                      // 72 MiB
    __bf16* Wws = (__bf16*)(ws + 75497472);         // 72 MiB
    float*  Pws = (float*)(ws + 150994944);         // 1024*4096*4 = 16 MiB (total 160 MiB)

    const float* w0 = w;
    const float* w1 = w + (size_t)64 * 768 * 32;

    // Stage 1: M and W in ONE launch (first 2304 blocks = M, last 2304 = W)
    gram_v4<<<4608, 256, 0, stream>>>(X, Y, w0, w1, Mws, Wws);
    // Stage 2: split-K partials, R1 config: 1024 single-wave blocks x 18 steps
    zpartial<<<1024, 64, 0, stream>>>(Mws, Wws, Pws, 18);
    // Stage 3: reduce + bias + softmax
    finalize<<<64, 256, 0, stream>>>(Pws, bias, out, 1024);
}

// Round 7
// 215.513 us; speedup vs baseline: 1.3239x; 1.2559x over previous
//
#include <hip/hip_runtime.h>
#include <hip/hip_bf16.h>

// z[b,n] = (1/196) * sum_{c,c'} (Xf[b] Yf[b]^T)[c,c'] * (w0[n] w1[n]^T)[c,c'] ; out = softmax_n(z + bias)
// M and W share a FRAG-PACKED layout (any (c,c') permutation applied to both preserves the
// trace-dot): flat = tile*16384 + wave*4096 + pair*512 + lane*8 + half*4 + e  (pair=frag>>1).
// Stage 1 (ONE launch, 4608 blocks): bid<2304 -> M[b] (bf16 /196, XCD-swizzled); else W[n].
// Stage 2: split-K partials (f32)  -> zpartial, 1024 single-wave blocks x 18 steps (R1 config)
// Stage 3: reduce + bias + softmax -> finalize, 64 blocks x 1024 threads (16-way split, unroll 8)

typedef float f32x4 __attribute__((ext_vector_type(4)));
typedef __bf16 bf16x8 __attribute__((ext_vector_type(8)));
typedef __bf16 bf16x4 __attribute__((ext_vector_type(4)));

#define KFLAT ((size_t)(768 * 768))
#define LDP 40   // padded LDS row: 80 B stride, keeps 16-B alignment; ~2-way aliasing

// Unified Gram kernel. First 2304 blocks: M[b] = X Y^T / 196 (K=196: 6 full + 4-tail).
// Last 2304 blocks: W[n] = w0 w1^T (K=32: 1 full step, no tail).
__global__ __launch_bounds__(256) void gram_v4(
    const float* __restrict__ X, const float* __restrict__ Y,
    const float* __restrict__ w0, const float* __restrict__ w1,
    __bf16* __restrict__ Mout, __bf16* __restrict__ Wout)
{
    const int t    = threadIdx.x;
    const int lane = t & 63;
    const int wid  = t >> 6;
    const int wr   = wid >> 1, wc = wid & 1;
    const int lr   = lane & 15, lq = lane >> 4;

    const bool wmode = (blockIdx.x >= 2304);
    int bx, bat, lda, nfull, tail;
    const float *A, *B;
    __bf16* Out;
    float scale;
    if (!wmode) {
        const int orig = (blockIdx.x & 7) * 288 + (blockIdx.x >> 3);  // XCD swizzle
        bat = orig / 36; bx = orig % 36;
        A = X + (size_t)bat * (768 * 196);
        B = Y + (size_t)bat * (768 * 196);
        Out = Mout; lda = 196; nfull = 6; tail = 1; scale = 1.0f / 196.0f;
    } else {
        const int wbid = blockIdx.x - 2304;
        bat = wbid / 36; bx = wbid % 36;
        A = w0 + (size_t)bat * (768 * 32);
        B = w1 + (size_t)bat * (768 * 32);
        Out = Wout; lda = 32; nfull = 1; tail = 0; scale = 1.0f;
    }
    const int c0 = (bx / 6) * 128, cc0 = (bx % 6) * 128;

    __shared__ __bf16 As[128][LDP];
    __shared__ __bf16 Bs[128][LDP];

    const int r = t >> 1;          // staging row 0..127
    const int h = t & 1;           // k-half (16 elems)
    const float* Ap = A + (size_t)(c0  + r) * lda + h * 16;
    const float* Bp = B + (size_t)(cc0 + r) * lda + h * 16;

    f32x4 acc[4][4];
#pragma unroll
    for (int i = 0; i < 4; ++i)
#pragma unroll
        for (int j = 0; j < 4; ++j) acc[i][j] = (f32x4){0.f, 0.f, 0.f, 0.f};

    auto stage = [&](const f32x4* va, const f32x4* vb) {
        bf16x8 u;
#pragma unroll
        for (int e = 0; e < 4; ++e) { u[e] = (__bf16)va[0][e]; u[e+4] = (__bf16)va[1][e]; }
        *(bf16x8*)&As[r][h * 16] = u;
#pragma unroll
        for (int e = 0; e < 4; ++e) { u[e] = (__bf16)va[2][e]; u[e+4] = (__bf16)va[3][e]; }
        *(bf16x8*)&As[r][h * 16 + 8] = u;
#pragma unroll
        for (int e = 0; e < 4; ++e) { u[e] = (__bf16)vb[0][e]; u[e+4] = (__bf16)vb[1][e]; }
        *(bf16x8*)&Bs[r][h * 16] = u;
#pragma unroll
        for (int e = 0; e < 4; ++e) { u[e] = (__bf16)vb[2][e]; u[e+4] = (__bf16)vb[3][e]; }
        *(bf16x8*)&Bs[r][h * 16 + 8] = u;
    };

    auto compute = [&]() {
        bf16x8 af[4], bfr[4];
#pragma unroll
        for (int m = 0; m < 4; ++m) af[m]  = *(const bf16x8*)&As[wr * 64 + m * 16 + lr][lq * 8];
#pragma unroll
        for (int n = 0; n < 4; ++n) bfr[n] = *(const bf16x8*)&Bs[wc * 64 + n * 16 + lr][lq * 8];
#pragma unroll
        for (int m = 0; m < 4; ++m)
#pragma unroll
            for (int n = 0; n < 4; ++n)
                acc[m][n] = __builtin_amdgcn_mfma_f32_16x16x32_bf16(af[m], bfr[n], acc[m][n], 0, 0, 0);
    };

    f32x4 pa[4], pb[4], na[4], nb[4];
#pragma unroll
    for (int j = 0; j < 4; ++j) {
        pa[j] = *(const f32x4*)(Ap + j * 4); pb[j] = *(const f32x4*)(Bp + j * 4);
        na[j] = (f32x4){0.f, 0.f, 0.f, 0.f}; nb[j] = (f32x4){0.f, 0.f, 0.f, 0.f};
    }

    for (int kk = 0; kk < nfull; ++kk) {
        __syncthreads();
        stage(pa, pb);
        if (kk + 1 < nfull) {
            const int o = (kk + 1) * 32;
#pragma unroll
            for (int j = 0; j < 4; ++j) { na[j] = *(const f32x4*)(Ap + o + j * 4); nb[j] = *(const f32x4*)(Bp + o + j * 4); }
        }
        __syncthreads();
        compute();
#pragma unroll
        for (int j = 0; j < 4; ++j) { pa[j] = na[j]; pb[j] = nb[j]; }
    }

    if (tail) {  // 4 valid k-cols at nfull*32, rest zero
        __syncthreads();
        const int tr = t & 127;
        const float* src = (t < 128) ? (A + (size_t)(c0  + tr) * lda + nfull * 32)
                                     : (B + (size_t)(cc0 + tr) * lda + nfull * 32);
        f32x4 v = *(const f32x4*)src;
        __bf16* dst = (t < 128) ? &As[tr][0] : &Bs[tr][0];
        bf16x4 q4 = { (__bf16)v.x, (__bf16)v.y, (__bf16)v.z, (__bf16)v.w };
        bf16x4 z4; bf16x8 z8;
#pragma unroll
        for (int e = 0; e < 4; ++e) z4[e] = (__bf16)0.0f;
#pragma unroll
        for (int e = 0; e < 8; ++e) z8[e] = (__bf16)0.0f;
        *(bf16x4*)dst        = q4;
        *(bf16x4*)(dst + 4)  = z4;
        *(bf16x8*)(dst + 8)  = z8;
        *(bf16x8*)(dst + 16) = z8;
        *(bf16x8*)(dst + 24) = z8;
        __syncthreads();
        compute();
    }

    // frag-packed output: 8 stores of 16 B/lane (pair-packed: frags 2p and 2p+1)
    __bf16* Ob = Out + (size_t)bat * KFLAT + (size_t)bx * 16384 + wid * 4096 + lane * 8;
#pragma unroll
    for (int p = 0; p < 8; ++p) {
        const int f0 = p * 2, f1 = f0 + 1;
        const f32x4 u0 = acc[f0 >> 2][f0 & 3];
        const f32x4 u1 = acc[f1 >> 2][f1 & 3];
        bf16x8 o;
#pragma unroll
        for (int e = 0; e < 4; ++e) { o[e] = (__bf16)(u0[e] * scale); o[e + 4] = (__bf16)(u1[e] * scale); }
        *(bf16x8*)(Ob + p * 512) = o;
    }
}

// Split-K, R1 config (measured best): 1024 single-wave blocks, 18 k-steps each.
// Each block writes its 64x64 f32 partial row-major to P[blk*4096 + ...].
__global__ __launch_bounds__(64) void zpartial(
    const __bf16* __restrict__ M, const __bf16* __restrict__ W,
    float* __restrict__ P, int steps)
{
    const int lane = threadIdx.x;
    const int lr = lane & 15, lq = lane >> 4;
    const size_t KK = KFLAT;  // 589824

    f32x4 acc[4][4];
#pragma unroll
    for (int i = 0; i < 4; ++i)
#pragma unroll
        for (int j = 0; j < 4; ++j) acc[i][j] = (f32x4){0.f, 0.f, 0.f, 0.f};

    const size_t s0 = (size_t)blockIdx.x * steps;
    for (int s = 0; s < steps; ++s) {
        const size_t k = (s0 + s) * 32 + (size_t)lq * 8;
        bf16x8 a[4], b[4];
#pragma unroll
        for (int i = 0; i < 4; ++i) a[i] = *(const bf16x8*)(M + (size_t)(i * 16 + lr) * KK + k);
#pragma unroll
        for (int j = 0; j < 4; ++j) b[j] = *(const bf16x8*)(W + (size_t)(j * 16 + lr) * KK + k);
#pragma unroll
        for (int i = 0; i < 4; ++i)
#pragma unroll
            for (int j = 0; j < 4; ++j)
                acc[i][j] = __builtin_amdgcn_mfma_f32_16x16x32_bf16(a[i], b[j], acc[i][j], 0, 0, 0);
    }

    float* Pb = P + (size_t)blockIdx.x * 4096;
#pragma unroll
    for (int i = 0; i < 4; ++i)
#pragma unroll
        for (int j = 0; j < 4; ++j)
#pragma unroll
            for (int e = 0; e < 4; ++e) {
                const int row = i * 16 + lq * 4 + e;
                const int col = j * 16 + lr;
                Pb[row * 64 + col] = acc[i][j][e];
            }
}

// Reduce partials + bias + softmax. 64 blocks (b) x 1024 threads: 16-way chunk split per n,
// explicit unroll 8 so 8 independent strided loads stay in flight per thread.
__global__ __launch_bounds__(1024) void finalize(
    const float* __restrict__ P, const float* __restrict__ bias,
    float* __restrict__ out, int nchunks)
{
    __shared__ float red[16][64];
    const int b = blockIdx.x, n = threadIdx.x & 63, q = threadIdx.x >> 6;
    const int iters = nchunks >> 4;          // chunks handled per q-slice
    const float* p = P + (size_t)q * 4096 + b * 64 + n;
    float s = 0.f;
#pragma unroll 8
    for (int c = 0; c < iters; ++c) s += p[(size_t)c * 16 * 4096];
    red[q][n] = s;
    __syncthreads();
    if (q == 0) {
        float z = bias[n];
#pragma unroll
        for (int i = 0; i < 16; ++i) z += red[i][n];
        float mx = z;
#pragma unroll
        for (int off = 32; off; off >>= 1) mx = fmaxf(mx, __shfl_xor(mx, off));
        float e = __expf(z - mx);
        float den = e;
#pragma unroll
        for (int off = 32; off; off >>= 1) den += __shfl_xor(den, off);
        out[b * 64 + n] = e / den;
    }
}

extern "C" void kernel_launch(void* const* d_in, const int* in_sizes, int n_in,
                              void* d_out, int out_size, void* d_ws, size_t ws_size,
                              hipStream_t stream) {
    const float* X    = (const float*)d_in[0];  // [64,768,14,14]
    const float* Y    = (const float*)d_in[1];  // [64,768,14,14]
    const float* w    = (const float*)d_in[2];  // [2,64,768,32]
    const float* bias = (const float*)d_in[3];  // [64]
    float* out = (float*)d_out;                 // [64,64] f32

    char* ws = (char*)d_ws;
    __bf16* Mws = (__bf16*)ws;                      // 72 MiB
    __bf16* Wws = (__bf16*)(ws + 75497472);         // 72 MiB
    float*  Pws = (float*)(ws + 150994944);         // 1024*4096*4 = 16 MiB (total 160 MiB)

    const float* w0 = w;
    const float* w1 = w + (size_t)64 * 768 * 32;

    // Stage 1: M and W in ONE launch (first 2304 blocks = M, last 2304 = W)
    gram_v4<<<4608, 256, 0, stream>>>(X, Y, w0, w1, Mws, Wws);
    // Stage 2: split-K partials, R1 config: 1024 single-wave blocks x 18 steps
    zpartial<<<1024, 64, 0, stream>>>(Mws, Wws, Pws, 18);
    // Stage 3: reduce + bias + softmax (16-way split, 8 loads in flight per thread)
    finalize<<<64, 1024, 0, stream>>>(Pws, bias, out, 1024);
}

// Round 8
// 201.424 us; speedup vs baseline: 1.4165x; 1.0699x over previous
//
#include <hip/hip_runtime.h>
#include <hip/hip_bf16.h>

// z[b,n] = (1/196) * sum_{c,c'} (Xf[b] Yf[b]^T)[c,c'] * (w0[n] w1[n]^T)[c,c'] ; out = softmax_n(z + bias)
// M and W share a FRAG-PACKED layout (any (c,c') permutation applied to both preserves the
// trace-dot): flat = tile*16384 + wave*4096 + pair*512 + lane*8 + half*4 + e  (pair=frag>>1).
// Stage 0: precast -> Xb,Yb bf16 [768][224] zero-padded; w -> bf16 flat   (ws high region)
// Stage 1 (ONE launch, 4608 blocks): bid<2304 -> M[b] (bf16 /196, XCD-swizzled); else W[n].
// Stage 2: split-K partials (f32)  -> zpartial, 1024 single-wave blocks x 18 steps  [UNCHANGED]
// Stage 3: reduce + bias + softmax -> finalize, 64 x 1024                            [UNCHANGED]
//
// ws map (192 MiB): M@0 (72Mi) | W@75497472 (72Mi) | P@150994944 (16Mi, overlaps Xb - disjoint
// lifetime: precast->Xb, gram reads Xb, then zpartial writes P) | Xb@150994944 | Yb@173015040 |
// w01b@195035136 | end 201326592.

typedef float f32x4 __attribute__((ext_vector_type(4)));
typedef __bf16 bf16x8 __attribute__((ext_vector_type(8)));
typedef __bf16 bf16x4 __attribute__((ext_vector_type(4)));

#define KFLAT ((size_t)(768 * 768))
#define LDP 40

// ---- Stage 0: cast/pad. ids [0,5505024): X/Y rows (49152 rows x 56 bf16x4-chunks each);
// ids [5505024, 6291456): w flat (786432 chunks). Grid exactly 24576 x 256.
__global__ __launch_bounds__(256) void precast(
    const float* __restrict__ X, const float* __restrict__ Y,
    const float* __restrict__ w,
    __bf16* __restrict__ Xb, __bf16* __restrict__ Yb,
    __bf16* __restrict__ w01b)
{
    const int id = blockIdx.x * 256 + threadIdx.x;
    if (id < 5505024) {
        const int half = id / 2752512;       // 0=X, 1=Y
        const int rid  = id - half * 2752512;
        const int row  = rid / 56;           // b*768 + c
        const int ch   = rid - row * 56;     // 0..55
        __bf16* dst = (half ? Yb : Xb) + (size_t)row * 224 + ch * 4;
        bf16x4 o;
        if (ch < 49) {
            const float* src = (half ? Y : X) + (size_t)row * 196 + ch * 4;
            f32x4 v = *(const f32x4*)src;
            o[0] = (__bf16)v.x; o[1] = (__bf16)v.y; o[2] = (__bf16)v.z; o[3] = (__bf16)v.w;
        } else {
#pragma unroll
            for (int e = 0; e < 4; ++e) o[e] = (__bf16)0.0f;
        }
        *(bf16x4*)dst = o;
    } else {
        const int wid2 = id - 5505024;       // 0..786431
        f32x4 v = *(const f32x4*)(w + (size_t)wid2 * 4);
        bf16x4 o = { (__bf16)v.x, (__bf16)v.y, (__bf16)v.z, (__bf16)v.w };
        *(bf16x4*)(w01b + (size_t)wid2 * 4) = o;
    }
}

// ---- Stage 1: unified Gram kernel, bf16 inputs, depth-2 prefetch, uniform k-steps.
// First 2304 blocks: M[b] = Xb Yb^T / 196 (7 steps over padded K=224). Last 2304: W[n] (1 step).
__global__ __launch_bounds__(256) void gram_v5(
    const __bf16* __restrict__ Xb, const __bf16* __restrict__ Yb,
    const __bf16* __restrict__ w01b,
    __bf16* __restrict__ Mout, __bf16* __restrict__ Wout)
{
    const int t    = threadIdx.x;
    const int lane = t & 63;
    const int wid  = t >> 6;
    const int wr   = wid >> 1, wc = wid & 1;
    const int lr   = lane & 15, lq = lane >> 4;

    const bool wmode = (blockIdx.x >= 2304);
    int bx, bat, lda, nfull;
    const __bf16 *A, *B;
    __bf16* Out;
    float scale;
    if (!wmode) {
        const int orig = (blockIdx.x & 7) * 288 + (blockIdx.x >> 3);  // XCD swizzle
        bat = orig / 36; bx = orig % 36;
        A = Xb + (size_t)bat * (768 * 224);
        B = Yb + (size_t)bat * (768 * 224);
        Out = Mout; lda = 224; nfull = 7; scale = 1.0f / 196.0f;
    } else {
        const int wbid = blockIdx.x - 2304;
        bat = wbid / 36; bx = wbid % 36;
        A = w01b + (size_t)bat * (768 * 32);
        B = w01b + (size_t)(64 * 768 * 32) + (size_t)bat * (768 * 32);
        Out = Wout; lda = 32; nfull = 1; scale = 1.0f;
    }
    const int c0 = (bx / 6) * 128, cc0 = (bx % 6) * 128;

    __shared__ __bf16 As[128][LDP];
    __shared__ __bf16 Bs[128][LDP];

    const int r = t >> 1;          // staging row 0..127
    const int h = t & 1;           // k-half (16 elems)
    const __bf16* Ap = A + (size_t)(c0  + r) * lda + h * 16;
    const __bf16* Bp = B + (size_t)(cc0 + r) * lda + h * 16;

    f32x4 acc[4][4];
#pragma unroll
    for (int i = 0; i < 4; ++i)
#pragma unroll
        for (int j = 0; j < 4; ++j) acc[i][j] = (f32x4){0.f, 0.f, 0.f, 0.f};

    auto compute = [&]() {
        bf16x8 af[4], bfr[4];
#pragma unroll
        for (int m = 0; m < 4; ++m) af[m]  = *(const bf16x8*)&As[wr * 64 + m * 16 + lr][lq * 8];
#pragma unroll
        for (int n = 0; n < 4; ++n) bfr[n] = *(const bf16x8*)&Bs[wc * 64 + n * 16 + lr][lq * 8];
#pragma unroll
        for (int m = 0; m < 4; ++m)
#pragma unroll
            for (int n = 0; n < 4; ++n)
                acc[m][n] = __builtin_amdgcn_mfma_f32_16x16x32_bf16(af[m], bfr[n], acc[m][n], 0, 0, 0);
    };

    auto ld = [&](int kk, bf16x8& x0, bf16x8& x1, bf16x8& y0, bf16x8& y1) {
        x0 = *(const bf16x8*)(Ap + kk * 32);
        x1 = *(const bf16x8*)(Ap + kk * 32 + 8);
        y0 = *(const bf16x8*)(Bp + kk * 32);
        y1 = *(const bf16x8*)(Bp + kk * 32 + 8);
    };

    bf16x8 a0, a1, b0, b1, n0, n1, n2, n3, t0, t1, t2, t3;
    ld(0, a0, a1, b0, b1);
    if (nfull > 1) ld(1, n0, n1, n2, n3);
    else { n0 = a0; n1 = a1; n2 = b0; n3 = b1; }
    t0 = a0; t1 = a1; t2 = b0; t3 = b1;

    for (int kk = 0; kk < nfull; ++kk) {
        __syncthreads();
        *(bf16x8*)&As[r][h * 16]     = a0;
        *(bf16x8*)&As[r][h * 16 + 8] = a1;
        *(bf16x8*)&Bs[r][h * 16]     = b0;
        *(bf16x8*)&Bs[r][h * 16 + 8] = b1;
        if (kk + 2 < nfull) ld(kk + 2, t0, t1, t2, t3);   // depth-2 prefetch
        __syncthreads();
        compute();
        a0 = n0; a1 = n1; b0 = n2; b1 = n3;
        n0 = t0; n1 = t1; n2 = t2; n3 = t3;
    }

    // frag-packed output: 8 stores of 16 B/lane (pair-packed: frags 2p and 2p+1)
    __bf16* Ob = Out + (size_t)bat * KFLAT + (size_t)bx * 16384 + wid * 4096 + lane * 8;
#pragma unroll
    for (int p = 0; p < 8; ++p) {
        const int f0 = p * 2, f1 = f0 + 1;
        const f32x4 u0 = acc[f0 >> 2][f0 & 3];
        const f32x4 u1 = acc[f1 >> 2][f1 & 3];
        bf16x8 o;
#pragma unroll
        for (int e = 0; e < 4; ++e) { o[e] = (__bf16)(u0[e] * scale); o[e + 4] = (__bf16)(u1[e] * scale); }
        *(bf16x8*)(Ob + p * 512) = o;
    }
}

// ---- Stage 2: split-K (UNCHANGED from R7): 1024 single-wave blocks, 18 k-steps each.
__global__ __launch_bounds__(64) void zpartial(
    const __bf16* __restrict__ M, const __bf16* __restrict__ W,
    float* __restrict__ P, int steps)
{
    const int lane = threadIdx.x;
    const int lr = lane & 15, lq = lane >> 4;
    const size_t KK = KFLAT;  // 589824

    f32x4 acc[4][4];
#pragma unroll
    for (int i = 0; i < 4; ++i)
#pragma unroll
        for (int j = 0; j < 4; ++j) acc[i][j] = (f32x4){0.f, 0.f, 0.f, 0.f};

    const size_t s0 = (size_t)blockIdx.x * steps;
    for (int s = 0; s < steps; ++s) {
        const size_t k = (s0 + s) * 32 + (size_t)lq * 8;
        bf16x8 a[4], b[4];
#pragma unroll
        for (int i = 0; i < 4; ++i) a[i] = *(const bf16x8*)(M + (size_t)(i * 16 + lr) * KK + k);
#pragma unroll
        for (int j = 0; j < 4; ++j) b[j] = *(const bf16x8*)(W + (size_t)(j * 16 + lr) * KK + k);
#pragma unroll
        for (int i = 0; i < 4; ++i)
#pragma unroll
            for (int j = 0; j < 4; ++j)
                acc[i][j] = __builtin_amdgcn_mfma_f32_16x16x32_bf16(a[i], b[j], acc[i][j], 0, 0, 0);
    }

    float* Pb = P + (size_t)blockIdx.x * 4096;
#pragma unroll
    for (int i = 0; i < 4; ++i)
#pragma unroll
        for (int j = 0; j < 4; ++j)
#pragma unroll
            for (int e = 0; e < 4; ++e) {
                const int row = i * 16 + lq * 4 + e;
                const int col = j * 16 + lr;
                Pb[row * 64 + col] = acc[i][j][e];
            }
}

// ---- Stage 3: reduce + bias + softmax (UNCHANGED from R7).
__global__ __launch_bounds__(1024) void finalize(
    const float* __restrict__ P, const float* __restrict__ bias,
    float* __restrict__ out, int nchunks)
{
    __shared__ float red[16][64];
    const int b = blockIdx.x, n = threadIdx.x & 63, q = threadIdx.x >> 6;
    const int iters = nchunks >> 4;
    const float* p = P + (size_t)q * 4096 + b * 64 + n;
    float s = 0.f;
#pragma unroll 8
    for (int c = 0; c < iters; ++c) s += p[(size_t)c * 16 * 4096];
    red[q][n] = s;
    __syncthreads();
    if (q == 0) {
        float z = bias[n];
#pragma unroll
        for (int i = 0; i < 16; ++i) z += red[i][n];
        float mx = z;
#pragma unroll
        for (int off = 32; off; off >>= 1) mx = fmaxf(mx, __shfl_xor(mx, off));
        float e = __expf(z - mx);
        float den = e;
#pragma unroll
        for (int off = 32; off; off >>= 1) den += __shfl_xor(den, off);
        out[b * 64 + n] = e / den;
    }
}

extern "C" void kernel_launch(void* const* d_in, const int* in_sizes, int n_in,
                              void* d_out, int out_size, void* d_ws, size_t ws_size,
                              hipStream_t stream) {
    const float* X    = (const float*)d_in[0];  // [64,768,14,14]
    const float* Y    = (const float*)d_in[1];  // [64,768,14,14]
    const float* w    = (const float*)d_in[2];  // [2,64,768,32]
    const float* bias = (const float*)d_in[3];  // [64]
    float* out = (float*)d_out;                 // [64,64] f32

    char* ws = (char*)d_ws;
    __bf16* Mws  = (__bf16*)ws;                      // @0,         72 MiB (same as R7)
    __bf16* Wws  = (__bf16*)(ws + 75497472);         // @72Mi,      72 MiB (same as R7)
    float*  Pws  = (float*)(ws + 150994944);         // @144Mi,     16 MiB (same as R7; overlaps Xb, disjoint lifetime)
    __bf16* Xbws = (__bf16*)(ws + 150994944);        // @144Mi,     21 MiB
    __bf16* Ybws = (__bf16*)(ws + 173015040);        // @165Mi,     21 MiB
    __bf16* wbws = (__bf16*)(ws + 195035136);        // @186Mi,      6 MiB  (total 192 MiB)

    // Stage 0: cast/pad inputs to bf16
    precast<<<24576, 256, 0, stream>>>(X, Y, w, Xbws, Ybws, wbws);
    // Stage 1: M and W in ONE launch (first 2304 blocks = M, last 2304 = W)
    gram_v5<<<4608, 256, 0, stream>>>(Xbws, Ybws, wbws, Mws, Wws);
    // Stage 2: split-K partials (unchanged)
    zpartial<<<1024, 64, 0, stream>>>(Mws, Wws, Pws, 18);
    // Stage 3: reduce + bias + softmax (unchanged)
    finalize<<<64, 1024, 0, stream>>>(Pws, bias, out, 1024);
}